// Round 6
// baseline (116.993 us; speedup 1.0000x reference)
//
#include <hip/hip_runtime.h>

// Fused: h = emb[:, :256] @ W_enc + b_enc ; LayerNorm(h)*gamma+beta ; ReLU
// (topology branch of the reference is a provable no-op: pooled == embeddings)
//
// Round 6: zero-LDS streaming K-loop. R3/R4/R5 (LDS-B+barriers, direct-B
// @2blk/CU, direct-B @4blk/CU) were all ~equal -> limiter is the A-staging
// LDS round-trip (cold load -> pack -> 16-way-conflicted ds_write -> barrier
// -> ds_read) common to all three. Now each lane loads its A fragment
// directly from global (L1-resident across the block's 4 waves) and packs
// in-register. No LDS except 512 B LN scratch; no barrier before epilogue.

typedef unsigned int uint32;
typedef __attribute__((ext_vector_type(8))) short bf16x8;   // 8 bf16 = 4 VGPR
typedef __attribute__((ext_vector_type(4))) float floatx4;  // MFMA C/D

constexpr int D  = 512;   // output width (N)
constexpr int MB = 16;    // rows per block
constexpr float EPS = 1e-5f;

__device__ inline uint32 pack_bf2(float a, float b) {
    uint32 ua = __float_as_uint(a);
    ua += 0x7FFFu + ((ua >> 16) & 1u);          // RNE
    uint32 ub = __float_as_uint(b);
    ub += 0x7FFFu + ((ub >> 16) & 1u);
    return (ua >> 16) | (ub & 0xFFFF0000u);
}

// W [k=256][n=512] f32 -> Wp bf16, linear index (k8*512 + n)*8 + j  (j = k%8)
__global__ __launch_bounds__(256) void pack_w(const float* __restrict__ W,
                                              uint32* __restrict__ Wp) {
    const int t  = blockIdx.x * 256 + threadIdx.x;   // 0..16383
    const int k8 = t >> 9;                           // 0..31
    const int n  = t & 511;
    uint32 r[4];
    #pragma unroll
    for (int jj = 0; jj < 4; ++jj) {
        float v0 = W[(k8 * 8 + 2 * jj)     * D + n];
        float v1 = W[(k8 * 8 + 2 * jj + 1) * D + n];
        r[jj] = pack_bf2(v0, v1);
    }
    uint4 o; o.x = r[0]; o.y = r[1]; o.z = r[2]; o.w = r[3];
    ((uint4*)Wp)[t] = o;
}

__global__ __launch_bounds__(256, 3)
void topo_mfma(const float* __restrict__ emb,
               const uint32* __restrict__ Wp,
               const float* __restrict__ benc,
               const float* __restrict__ gamma,
               const float* __restrict__ beta,
               float* __restrict__ out)
{
    __shared__ float2 s_red[4][MB];    // per-wave row partials (sum, sumsq)

    const int t    = threadIdx.x;
    const int wv   = t >> 6;           // wave 0..3 -> cols wv*128 .. wv*128+127
    const int lane = t & 63;
    const int q    = lane >> 4;        // quad 0..3
    const int cl   = lane & 15;
    const long row0 = (long)blockIdx.x * MB;

    // Per-lane A base: row (row0+cl), k-offset q*8; chunk ch adds 32 floats
    // (128 B, fits the 13-bit signed imm as ch*128 / ch*128+16).
    const float* aptr = emb + (row0 + cl) * D + q * 8;

    floatx4 acc[8];                    // 32 regs/lane, ALL indices static
    #pragma unroll
    for (int n2 = 0; n2 < 8; ++n2)
        acc[n2] = (floatx4){0.f, 0.f, 0.f, 0.f};

    // ---- K loop: 8 chunks of k=32; A and B straight from global; NO LDS ----
    #pragma unroll 2
    for (int ch = 0; ch < 8; ++ch) {
        // A frag: lane holds A[m = cl][k = q*8+j], j=0..7, in-register packed
        float4 f0 = *(const float4*)(aptr + ch * 32);
        float4 f1 = *(const float4*)(aptr + ch * 32 + 4);
        uint4 au;
        au.x = pack_bf2(f0.x, f0.y); au.y = pack_bf2(f0.z, f0.w);
        au.z = pack_bf2(f1.x, f1.y); au.w = pack_bf2(f1.z, f1.w);
        bf16x8 af = __builtin_bit_cast(bf16x8, au);
        #pragma unroll
        for (int n2 = 0; n2 < 8; ++n2) {
            // B frag: lane holds B[k = (ch*4+q)*8 + j][n = (wv*8+n2)*16 + cl]
            bf16x8 bf = *(const bf16x8*)(Wp +
                ((ch * 4 + q) * 512 + (wv * 8 + n2) * 16 + cl) * 4);
            acc[n2] = __builtin_amdgcn_mfma_f32_16x16x32_bf16(af, bf, acc[n2], 0, 0, 0);
        }
    }

    // ---- epilogue: bias + cross-wave LayerNorm + ReLU ----
    // C/D layout: col = (wv*8+n2)*16 + cl, row_local = q*4 + reg
    float bv[8], sum[4] = {0.f, 0.f, 0.f, 0.f}, sq[4] = {0.f, 0.f, 0.f, 0.f};
    #pragma unroll
    for (int n2 = 0; n2 < 8; ++n2) bv[n2] = benc[(wv * 8 + n2) * 16 + cl];

    #pragma unroll
    for (int n2 = 0; n2 < 8; ++n2)
        #pragma unroll
        for (int r = 0; r < 4; ++r) {
            float v = acc[n2][r] + bv[n2];
            acc[n2][r] = v;
            sum[r] += v;
            sq[r] = fmaf(v, v, sq[r]);
        }
    // reduce across the 16 cl-lanes (xor 1,2,4,8 stays within the quad group)
    #pragma unroll
    for (int m = 1; m < 16; m <<= 1)
        #pragma unroll
        for (int r = 0; r < 4; ++r) {
            sum[r] += __shfl_xor(sum[r], m, 64);
            sq[r]  += __shfl_xor(sq[r],  m, 64);
        }
    if (cl == 0) {
        #pragma unroll
        for (int r = 0; r < 4; ++r)
            s_red[wv][q * 4 + r] = make_float2(sum[r], sq[r]);
    }
    __syncthreads();

    float mu[4], inv[4];
    #pragma unroll
    for (int r = 0; r < 4; ++r) {
        int row = q * 4 + r;
        float s = 0.f, ss = 0.f;
        #pragma unroll
        for (int w = 0; w < 4; ++w) {
            float2 v = s_red[w][row];
            s += v.x; ss += v.y;
        }
        float m_ = s * (1.f / 512.f);
        float var = ss * (1.f / 512.f) - m_ * m_;
        mu[r] = m_;
        inv[r] = rsqrtf(var + EPS);
    }

    #pragma unroll
    for (int n2 = 0; n2 < 8; ++n2) {
        int c = (wv * 8 + n2) * 16 + cl;
        float g = gamma[c], be = beta[c];
        float* op = out + (row0 + q * 4) * D + c;
        #pragma unroll
        for (int r = 0; r < 4; ++r) {
            float v = (acc[n2][r] - mu[r]) * inv[r] * g + be;
            op[r * D] = fmaxf(v, 0.f);
        }
    }
}

extern "C" void kernel_launch(void* const* d_in, const int* in_sizes, int n_in,
                              void* d_out, int out_size, void* d_ws, size_t ws_size,
                              hipStream_t stream) {
    // inputs: embeddings, W_proj, b_proj, W_enc, b_enc, ln_gamma, ln_beta
    const float* emb   = (const float*)d_in[0];
    const float* Wenc  = (const float*)d_in[3];
    const float* benc  = (const float*)d_in[4];
    const float* gamma = (const float*)d_in[5];
    const float* beta  = (const float*)d_in[6];
    float* outp = (float*)d_out;
    uint32* Wp = (uint32*)d_ws;            // 256 KB packed bf16 W

    pack_w<<<64, 256, 0, stream>>>(Wenc, Wp);
    const int rows = in_sizes[0] / D;      // 16384
    topo_mfma<<<rows / MB, 256, 0, stream>>>(emb, Wp, benc, gamma, beta, outp);
}

// Round 8
// 105.511 us; speedup vs baseline: 1.1088x; 1.1088x over previous
//
#include <hip/hip_runtime.h>

// Fused: h = emb[:, :256] @ W_enc + b_enc ; LayerNorm(h)*gamma+beta ; ReLU
// (topology branch of the reference is a provable no-op: pooled == embeddings)
//
// Round 8 = Round 7 theory with the compile fix (__builtin_nontemporal_* needs
// native ext_vector_type, not HIP_vector_type float4):
//  (a) epilogue through an LDS h-tile (aliased over dead A-tile): LN reduce
//      on row-major reads, float4 stores with 256 B/quad coalescing
//  (b) nontemporal out stores + nontemporal A loads (stop evicting Wp in L2)
//  (c) bias prefetch before the K-loop.

typedef unsigned int uint32;
typedef __attribute__((ext_vector_type(8))) short bf16x8;   // 8 bf16 = 4 VGPR
typedef __attribute__((ext_vector_type(4))) float floatx4;  // MFMA C/D + NT io

constexpr int D  = 512;   // output width (N)
constexpr int MB = 16;    // rows per block
constexpr int AP = 68;    // A-tile pitch in dwords (16 rows x 4 + 4 pad)
constexpr int HP = 516;   // h-tile pitch in floats (512 + 4 pad)
constexpr float EPS = 1e-5f;

__device__ inline uint32 pack_bf2(float a, float b) {
    uint32 ua = __float_as_uint(a);
    ua += 0x7FFFu + ((ua >> 16) & 1u);          // RNE
    uint32 ub = __float_as_uint(b);
    ub += 0x7FFFu + ((ub >> 16) & 1u);
    return (ua >> 16) | (ub & 0xFFFF0000u);
}

// W [k=256][n=512] f32 -> Wp bf16, linear index (k8*512 + n)*8 + j  (j = k%8)
__global__ __launch_bounds__(256) void pack_w(const float* __restrict__ W,
                                              uint32* __restrict__ Wp) {
    const int t  = blockIdx.x * 256 + threadIdx.x;   // 0..16383
    const int k8 = t >> 9;                           // 0..31
    const int n  = t & 511;
    uint32 r[4];
    #pragma unroll
    for (int jj = 0; jj < 4; ++jj) {
        float v0 = W[(k8 * 8 + 2 * jj)     * D + n];
        float v1 = W[(k8 * 8 + 2 * jj + 1) * D + n];
        r[jj] = pack_bf2(v0, v1);
    }
    uint4 o; o.x = r[0]; o.y = r[1]; o.z = r[2]; o.w = r[3];
    ((uint4*)Wp)[t] = o;
}

__global__ __launch_bounds__(256, 4)
void topo_mfma(const float* __restrict__ emb,
               const uint32* __restrict__ Wp,
               const float* __restrict__ benc,
               const float* __restrict__ gamma,
               const float* __restrict__ beta,
               float* __restrict__ out)
{
    // One 33 KB arena: A-tile [32][AP] uint32 (8.7 KB) during the K-loop,
    // then re-used (after a barrier) as the h-tile [16][HP] f32 (33 KB).
    __shared__ uint32 smem[MB * HP];
    uint32* s_a = smem;
    float*  s_h = (float*)smem;

    const int t    = threadIdx.x;
    const int wv   = t >> 6;           // wave 0..3 -> cols wv*128 .. wv*128+127
    const int lane = t & 63;
    const int q    = lane >> 4;        // quad 0..3
    const int cl   = lane & 15;
    const long row0 = (long)blockIdx.x * MB;

    // ---- stage A: 16 rows x 256 cols f32 -> bf16 [k8][m][8k] (NT loads) ----
    #pragma unroll
    for (int p = 0; p < 2; ++p) {
        int m  = p * 8 + (t >> 5);
        int k8 = t & 31;
        const floatx4* src = (const floatx4*)(emb + (row0 + m) * D + k8 * 8);
        floatx4 f0 = __builtin_nontemporal_load(src);
        floatx4 f1 = __builtin_nontemporal_load(src + 1);
        uint4 o;
        o.x = pack_bf2(f0.x, f0.y); o.y = pack_bf2(f0.z, f0.w);
        o.z = pack_bf2(f1.x, f1.y); o.w = pack_bf2(f1.z, f1.w);
        *(uint4*)&s_a[k8 * AP + m * 4] = o;
    }

    // bias prefetch (needed only after the K-loop)
    float bv[8];
    #pragma unroll
    for (int n2 = 0; n2 < 8; ++n2) bv[n2] = benc[(wv * 8 + n2) * 16 + cl];

    __syncthreads();

    floatx4 acc[8];                    // 32 regs/lane, ALL indices static
    #pragma unroll
    for (int n2 = 0; n2 < 8; ++n2)
        acc[n2] = (floatx4){0.f, 0.f, 0.f, 0.f};

    // ---- K loop: 8 chunks of k=32; B frags straight from L2, no barriers ----
    #pragma unroll 2
    for (int ch = 0; ch < 8; ++ch) {
        // A frag: lane holds A[m = cl][k = q*8+j]
        bf16x8 af = *(const bf16x8*)&s_a[(ch * 4 + q) * AP + cl * 4];
        #pragma unroll
        for (int n2 = 0; n2 < 8; ++n2) {
            // B frag: lane holds B[k = (ch*4+q)*8 + j][n = (wv*8+n2)*16 + cl]
            bf16x8 bf = *(const bf16x8*)(Wp +
                ((ch * 4 + q) * 512 + (wv * 8 + n2) * 16 + cl) * 4);
            acc[n2] = __builtin_amdgcn_mfma_f32_16x16x32_bf16(af, bf, acc[n2], 0, 0, 0);
        }
    }

    __syncthreads();                   // A-tile dead; smem becomes h-tile

    // ---- park h = acc + bias in LDS (C/D layout: col=(wv*8+n2)*16+cl,
    //      row = q*4 + r). Bank-checked: 2-way max (free). ----
    #pragma unroll
    for (int n2 = 0; n2 < 8; ++n2)
        #pragma unroll
        for (int r = 0; r < 4; ++r)
            s_h[(q * 4 + r) * HP + (wv * 8 + n2) * 16 + cl] = acc[n2][r] + bv[n2];
    __syncthreads();

    // ---- LN + ReLU on row-major re-read; 16 threads own one row ----
    const int row = t >> 4;            // 0..15
    const int c0  = (t & 15) * 4;      // this thread: cols c0 + j*64, 4 wide
    floatx4 f[8];
    float s = 0.f, ss = 0.f;
    #pragma unroll
    for (int j = 0; j < 8; ++j) {
        f[j] = *(const floatx4*)&s_h[row * HP + c0 + j * 64];
        s  += f[j].x + f[j].y + f[j].z + f[j].w;
        ss += f[j].x * f[j].x + f[j].y * f[j].y
            + f[j].z * f[j].z + f[j].w * f[j].w;
    }
    // reduce across the 16 lanes sharing this row (xor 1,2,4,8 stays in-group)
    #pragma unroll
    for (int m = 1; m < 16; m <<= 1) {
        s  += __shfl_xor(s,  m, 64);
        ss += __shfl_xor(ss, m, 64);
    }
    const float mu  = s * (1.f / 512.f);
    const float var = ss * (1.f / 512.f) - mu * mu;
    const float inv = rsqrtf(var + EPS);

    float* orow = out + (row0 + row) * D;
    #pragma unroll
    for (int j = 0; j < 8; ++j) {
        const int c = c0 + j * 64;
        floatx4 g4 = *(const floatx4*)&gamma[c];
        floatx4 b4 = *(const floatx4*)&beta[c];
        floatx4 v;
        v.x = fmaxf((f[j].x - mu) * inv * g4.x + b4.x, 0.f);
        v.y = fmaxf((f[j].y - mu) * inv * g4.y + b4.y, 0.f);
        v.z = fmaxf((f[j].z - mu) * inv * g4.z + b4.z, 0.f);
        v.w = fmaxf((f[j].w - mu) * inv * g4.w + b4.w, 0.f);
        __builtin_nontemporal_store(v, (floatx4*)&orow[c]);   // 256 B/quad
    }
}

extern "C" void kernel_launch(void* const* d_in, const int* in_sizes, int n_in,
                              void* d_out, int out_size, void* d_ws, size_t ws_size,
                              hipStream_t stream) {
    // inputs: embeddings, W_proj, b_proj, W_enc, b_enc, ln_gamma, ln_beta
    const float* emb   = (const float*)d_in[0];
    const float* Wenc  = (const float*)d_in[3];
    const float* benc  = (const float*)d_in[4];
    const float* gamma = (const float*)d_in[5];
    const float* beta  = (const float*)d_in[6];
    float* outp = (float*)d_out;
    uint32* Wp = (uint32*)d_ws;            // 256 KB packed bf16 W

    pack_w<<<64, 256, 0, stream>>>(Wenc, Wp);
    const int rows = in_sizes[0] / D;      // 16384
    topo_mfma<<<rows / MB, 256, 0, stream>>>(emb, Wp, benc, gamma, beta, outp);
}